// Round 15
// baseline (242.561 us; speedup 1.0000x reference)
//
#include <hip/hip_runtime.h>

#define NN 100000     // nodes
#define NE 1600000    // edges
#define NG 512        // graphs
#define C_H1 64
#define C_H2 128
#define C_OUT 2

#define MM2_BLOCKS ((NN + 63) / 64)                   // 1563 (64 nodes/block)
#define NB ((NN + 255) >> 8)                          // 391 dst-buckets of 256 nodes
#define PCHUNKS 512                                   // partition chunks
#define PCHUNK_E (NE / PCHUNKS)                       // 3125 edges per chunk
#define AT_S 68                                       // padded A-tile row stride

// ---------------- radix partition phase 1: per-chunk bucket histograms -----------
__global__ void k_hist(const int* __restrict__ ei, int* __restrict__ hist) {
    __shared__ int lh[NB];
    int tid = threadIdx.x;
    int blk = blockIdx.x;
    for (int i = tid; i < NB; i += 256) lh[i] = 0;
    __syncthreads();
    int base = blk * PCHUNK_E;
    for (int e = base + tid; e < base + PCHUNK_E; e += 256)
        atomicAdd(&lh[ei[NE + e] >> 8], 1);
    __syncthreads();
    for (int i = tid; i < NB; i += 256) hist[i * PCHUNKS + blk] = lh[i];
}

// ---------------- phase 2a: per-bucket scan over chunks (bucket-relative) --------
__global__ void k_colscan0(const int* __restrict__ hist, int* __restrict__ offs,
                           int* __restrict__ btot) {
    __shared__ int sh[256];
    int b = blockIdx.x;
    int tid = threadIdx.x;
    int v0 = hist[b * PCHUNKS + 2 * tid];
    int v1 = hist[b * PCHUNKS + 2 * tid + 1];
    sh[tid] = v0 + v1;
    __syncthreads();
    for (int off = 1; off < 256; off <<= 1) {
        int v = (tid >= off) ? sh[tid - off] : 0;
        __syncthreads();
        sh[tid] += v;
        __syncthreads();
    }
    int base = (tid == 0) ? 0 : sh[tid - 1];
    offs[b * PCHUNKS + 2 * tid]     = base;
    offs[b * PCHUNKS + 2 * tid + 1] = base + v0;
    if (tid == 255) btot[b] = sh[255];
}

// ---------------- phase 2b: exclusive scan of 391 bucket totals ------------------
__global__ void k_bbase(const int* __restrict__ btot, int* __restrict__ bbase,
                        int* __restrict__ row_ptr) {
    __shared__ int sh[256];
    int tid = threadIdx.x;
    int v0 = (2 * tid     < NB) ? btot[2 * tid]     : 0;
    int v1 = (2 * tid + 1 < NB) ? btot[2 * tid + 1] : 0;
    sh[tid] = v0 + v1;
    __syncthreads();
    for (int off = 1; off < 256; off <<= 1) {
        int v = (tid >= off) ? sh[tid - off] : 0;
        __syncthreads();
        sh[tid] += v;
        __syncthreads();
    }
    int base = (tid == 0) ? 0 : sh[tid - 1];
    if (2 * tid     < NB) bbase[2 * tid]     = base;
    if (2 * tid + 1 < NB) bbase[2 * tid + 1] = base + v0;
    if (tid == 255) { bbase[NB] = sh[255]; row_ptr[NN] = sh[255]; }   // == NE
}

// ---------------- phase 3: scatter via LDS cursors (no global atomics) -----------
__global__ void k_scatterA(const int* __restrict__ ei, const int* __restrict__ offs,
                           const int* __restrict__ bbase, int2* __restrict__ ed2) {
    __shared__ int lcur[NB];
    int tid = threadIdx.x;
    int blk = blockIdx.x;
    for (int i = tid; i < NB; i += 256) lcur[i] = bbase[i] + offs[i * PCHUNKS + blk];
    __syncthreads();
    int base = blk * PCHUNK_E;
    for (int e = base + tid; e < base + PCHUNK_E; e += 256) {
        int s = ei[e], d = ei[NE + e];
        int pos = atomicAdd(&lcur[d >> 8], 1);     // LDS atomic, low contention
        int2 v; v.x = s; v.y = d;
        ed2[pos] = v;
    }
}

// ---------------- B1: bucket-local degree -> dinv + row_ptr (no global atomics) --
__global__ void k_B1(const int2* __restrict__ ed2, const int* __restrict__ bbase,
                     float* __restrict__ dinv, int* __restrict__ row_ptr) {
    __shared__ int ldeg[256];
    __shared__ int sh[256];
    int b = blockIdx.x;
    int tid = threadIdx.x;
    int lo = b << 8;
    ldeg[tid] = 0;
    __syncthreads();
    int beg = bbase[b], end = bbase[b + 1];
    for (int j = beg + tid; j < end; j += 256)
        atomicAdd(&ldeg[ed2[j].y - lo], 1);
    __syncthreads();
    int d = ldeg[tid];
    int node = lo + tid;
    if (node < NN) dinv[node] = rsqrtf((float)d + 1.0f);
    sh[tid] = d;
    __syncthreads();
    for (int off = 1; off < 256; off <<= 1) {
        int v = (tid >= off) ? sh[tid - off] : 0;
        __syncthreads();
        sh[tid] += v;
        __syncthreads();
    }
    int excl = beg + ((tid == 0) ? 0 : sh[tid - 1]);
    if (node < NN) row_ptr[node] = excl;
}

// ---------------- repack x to float4 rows (16B gathers downstream) ---------------
__global__ void k_x4(const float* __restrict__ x, float4* __restrict__ x4) {
    int n = blockIdx.x * blockDim.x + threadIdx.x;
    if (n >= NN) return;
    float4 v; v.x = x[n * 3]; v.y = x[n * 3 + 1]; v.z = x[n * 3 + 2]; v.w = 0.f;
    x4[n] = v;
}

// ---------------- scatter pass B + fused layer-1 aggregation (512 threads) -------
__global__ void k_scatterB(const int* __restrict__ row_ptr, const int2* __restrict__ ed2,
                           const float* __restrict__ dinv, const float4* __restrict__ x4,
                           int2* __restrict__ ed, float4* __restrict__ aggx4) {
    __shared__ int   lcur[256];
    __shared__ float ldin[256];
    __shared__ float lax[256 * 3];
    int b = blockIdx.x;
    int lo = b << 8;
    int tid = threadIdx.x;
    int node = lo + tid;
    if (tid < 256) {
        lcur[tid] = row_ptr[node < NN ? node : NN];
        ldin[tid] = (node < NN) ? dinv[node] : 0.f;
        lax[tid] = 0.f; lax[256 + tid] = 0.f; lax[512 + tid] = 0.f;
    }
    __syncthreads();
    int seg_beg = row_ptr[lo];
    int hi = lo + 256; if (hi > NN) hi = NN;
    int seg_end = row_ptr[hi];
    for (int j = seg_beg + tid; j < seg_end; j += 512) {
        int2 sd = ed2[j];
        int local = sd.y - lo;
        int pos = atomicAdd(&lcur[local], 1);
        float nrm = dinv[sd.x] * ldin[local];
        int2 v; v.x = sd.x; v.y = __float_as_int(nrm);
        ed[pos] = v;
        float4 xs = x4[sd.x];                          // 16B gather, L2-hot (1.6MB)
        atomicAdd(&lax[local],       nrm * xs.x);      // ds_add_f32
        atomicAdd(&lax[256 + local], nrm * xs.y);
        atomicAdd(&lax[512 + local], nrm * xs.z);
    }
    __syncthreads();
    if (tid < 256 && node < NN) {
        float di = ldin[tid];
        float s2 = di * di;
        float4 xs = x4[node];
        float4 a;
        a.x = lax[tid]       + s2 * xs.x;
        a.y = lax[256 + tid] + s2 * xs.y;
        a.z = lax[512 + tid] + s2 * xs.z;
        a.w = di;                                      // dinv rides along
        aggx4[node] = a;
    }
}

// ---------------- layer 2 aggregate via on-the-fly h1 recompute ------------------
__global__ void k_edge1(const int* __restrict__ row_ptr, const int2* __restrict__ ed,
                        const float4* __restrict__ aggx4,
                        const float* __restrict__ W1, const float* __restrict__ b1,
                        float* __restrict__ agg1) {
    __shared__ float4 lp[256];                        // 64 per wave
    int t = blockIdx.x * 256 + threadIdx.x;           // grid exact: NN*64/256
    int n = t >> 6, c = t & 63;
    int lane = threadIdx.x & 63;
    int wbase = threadIdx.x & 192;                    // wave's LDS base (0,64,128,192)

    float w0 = W1[c], w1 = W1[64 + c], w2 = W1[128 + c], bb = b1[c];
    float4 an = aggx4[n];                             // wave-uniform, .w = dinv
    float hself = fmaxf(fmaf(an.x, w0, fmaf(an.y, w1, fmaf(an.z, w2, bb))), 0.f);
    float acc = an.w * an.w * hself;

    int beg = row_ptr[n], end = row_ptr[n + 1];
    for (int base = beg; base < end; base += 64) {
        int m = end - base; if (m > 64) m = 64;
        if (lane < m) {
            int2 v = ed[base + lane];                 // coalesced 8B
            float4 ax = aggx4[v.x];                   // random 16B, L2-hot
            float4 p; p.x = ax.x; p.y = ax.y; p.z = ax.z; p.w = __int_as_float(v.y);
            lp[wbase + lane] = p;
        }
        int e = 0;
        for (; e + 3 < m; e += 4) {
            float4 p0 = lp[wbase + e];
            float4 p1 = lp[wbase + e + 1];
            float4 p2 = lp[wbase + e + 2];
            float4 p3 = lp[wbase + e + 3];
            float h0  = fmaxf(fmaf(p0.x, w0, fmaf(p0.y, w1, fmaf(p0.z, w2, bb))), 0.f);
            float h1v = fmaxf(fmaf(p1.x, w0, fmaf(p1.y, w1, fmaf(p1.z, w2, bb))), 0.f);
            float h2v = fmaxf(fmaf(p2.x, w0, fmaf(p2.y, w1, fmaf(p2.z, w2, bb))), 0.f);
            float h3v = fmaxf(fmaf(p3.x, w0, fmaf(p3.y, w1, fmaf(p3.z, w2, bb))), 0.f);
            acc = fmaf(p0.w, h0, acc);
            acc = fmaf(p1.w, h1v, acc);
            acc = fmaf(p2.w, h2v, acc);
            acc = fmaf(p3.w, h3v, acc);
        }
        for (; e < m; ++e) {
            float4 p = lp[wbase + e];
            float h = fmaxf(fmaf(p.x, w0, fmaf(p.y, w1, fmaf(p.z, w2, bb))), 0.f);
            acc = fmaf(p.w, h, acc);
        }
    }
    agg1[t] = acc;   // NO bias/relu here: h2 = relu(agg1 @ W2 + b2)
}

// ---------------- fused register-tiled GEMM + pool (v5: grid-size fix) ------------
// Block = 64 nodes x 128 ch, 256 threads, 4x8 micro-tile -> 1563 blocks (2x waves
// in flight vs v4). A-tile LDS 17.4 KB; W2 from global (L1-resident).
__global__ void k_mm2pool(const float* __restrict__ agg1, const float* __restrict__ W2,
                          const float* __restrict__ b2, const int* __restrict__ batch,
                          float* __restrict__ pooled) {
    __shared__ float at[64 * AT_S];        // 17.4 KiB
    __shared__ float lpool[4 * C_H2];      // 2 KiB
    int tid = threadIdx.x;
    {
        const float4* a4 = (const float4*)(agg1 + (size_t)blockIdx.x * 64 * C_H1);
        for (int i = tid; i < 64 * 16; i += 256) {
            int row = i >> 4, k4 = i & 15;
            *(float4*)&at[row * AT_S + k4 * 4] = a4[i];   // coalesced global read
        }
        for (int i = tid; i < 4 * C_H2; i += 256) lpool[i] = 0.f;
    }
    __syncthreads();

    int tx = tid & 15;            // channel group: 8 ch
    int my = tid >> 4;            // node group: 4 consecutive nodes
    int c0 = tx * 8;
    int m0 = my * 4;

    float acc[4][8];
#pragma unroll
    for (int i = 0; i < 4; ++i)
#pragma unroll
        for (int j = 0; j < 8; ++j) acc[i][j] = 0.f;

    for (int k0 = 0; k0 < C_H1; k0 += 4) {
        float4 wf[4][2];
#pragma unroll
        for (int kk = 0; kk < 4; ++kk) {
            wf[kk][0] = *(const float4*)&W2[(k0 + kk) * C_H2 + c0];      // global, L1-hot
            wf[kk][1] = *(const float4*)&W2[(k0 + kk) * C_H2 + c0 + 4];
        }
#pragma unroll
        for (int i = 0; i < 4; ++i) {
            float4 af = *(const float4*)&at[(m0 + i) * AT_S + k0];
#pragma unroll
            for (int kk = 0; kk < 4; ++kk) {
                float a = (kk == 0) ? af.x : (kk == 1) ? af.y : (kk == 2) ? af.z : af.w;
                acc[i][0] = fmaf(a, wf[kk][0].x, acc[i][0]);
                acc[i][1] = fmaf(a, wf[kk][0].y, acc[i][1]);
                acc[i][2] = fmaf(a, wf[kk][0].z, acc[i][2]);
                acc[i][3] = fmaf(a, wf[kk][0].w, acc[i][3]);
                acc[i][4] = fmaf(a, wf[kk][1].x, acc[i][4]);
                acc[i][5] = fmaf(a, wf[kk][1].y, acc[i][5]);
                acc[i][6] = fmaf(a, wf[kk][1].z, acc[i][6]);
                acc[i][7] = fmaf(a, wf[kk][1].w, acc[i][7]);
            }
        }
    }

    int nbase = blockIdx.x * 64 + m0;
    int gbase = batch[blockIdx.x * 64];                // block-uniform
    int gidx[4];
#pragma unroll
    for (int i = 0; i < 4; ++i)
        gidx[i] = (nbase + i < NN) ? batch[nbase + i] : -1;
    float bias[8];
#pragma unroll
    for (int j = 0; j < 8; ++j) bias[j] = b2[c0 + j];

#pragma unroll
    for (int j = 0; j < 8; ++j) {
        int run_g = -1;
        float rs = 0.f;
#pragma unroll
        for (int i = 0; i < 4; ++i) {
            if (gidx[i] < 0) break;
            float h = fmaxf(acc[i][j] + bias[j], 0.f);
            if (gidx[i] != run_g) {
                if (run_g >= 0) {
                    int slot = run_g - gbase;
                    if (slot < 4) atomicAdd(&lpool[slot * C_H2 + c0 + j], rs);
                    else          atomicAdd(&pooled[(run_g << 7) + c0 + j], rs);
                }
                run_g = gidx[i]; rs = h;
            } else {
                rs += h;
            }
        }
        if (run_g >= 0) {
            int slot = run_g - gbase;
            if (slot < 4) atomicAdd(&lpool[slot * C_H2 + c0 + j], rs);
            else          atomicAdd(&pooled[(run_g << 7) + c0 + j], rs);
        }
    }
    __syncthreads();
    for (int i = tid; i < 4 * C_H2; i += 256) {
        int slot = i >> 7, c = i & 127;
        int g = gbase + slot;
        float v = lpool[i];
        if (g < NG && v != 0.f) atomicAdd(&pooled[(g << 7) + c], v);
    }
}

// ---------------- FC: out = (pooled/cnt) @ Wfc + bfc ----------------
__device__ __forceinline__ int lower_bound(const int* __restrict__ a, int n, int key) {
    int lo = 0, hi = n;
    while (lo < hi) { int mid = (lo + hi) >> 1; if (a[mid] < key) lo = mid + 1; else hi = mid; }
    return lo;
}

__global__ void k_fc(const float* __restrict__ pooled, const int* __restrict__ batch,
                     const float* __restrict__ Wfc, const float* __restrict__ bfc,
                     float* __restrict__ out) {
    int t = blockIdx.x * blockDim.x + threadIdx.x;
    if (t >= NG * C_OUT) return;
    int g = t >> 1, o = t & 1;
    int start = lower_bound(batch, NN, g);
    int end   = lower_bound(batch, NN, g + 1);
    float inv = 1.f / fmaxf((float)(end - start), 1.f);
    float s = bfc[o];
    for (int cc = 0; cc < C_H2; ++cc)
        s = fmaf(pooled[(g << 7) + cc] * inv, Wfc[cc * C_OUT + o], s);
    out[t] = s;
}

extern "C" void kernel_launch(void* const* d_in, const int* in_sizes, int n_in,
                              void* d_out, int out_size, void* d_ws, size_t ws_size,
                              hipStream_t stream) {
    const float* x     = (const float*)d_in[0];
    const int*   ei    = (const int*)d_in[1];   // [2, E]: row0 = src, row1 = dst
    const int*   batch = (const int*)d_in[2];
    const float* W1    = (const float*)d_in[3];
    const float* b1    = (const float*)d_in[4];
    const float* W2    = (const float*)d_in[5];
    const float* b2    = (const float*)d_in[6];
    const float* Wfc   = (const float*)d_in[7];
    const float* bfc   = (const float*)d_in[8];
    float* out = (float*)d_out;

    // workspace carve-out (~58 MB)
    char* p = (char*)d_ws;
    auto alloc = [&](size_t bytes) { char* r = p; p += (bytes + 255) & ~size_t(255); return r; };
    float*  dinv    = (float*) alloc((size_t)NN * 4);
    int*    row_ptr = (int*)   alloc((size_t)(NN + 1) * 4);
    int*    btot    = (int*)   alloc((size_t)NB * 4);
    int*    bbase   = (int*)   alloc((size_t)(NB + 1) * 4);
    int*    hist    = (int*)   alloc((size_t)NB * PCHUNKS * 4);
    int*    offs    = (int*)   alloc((size_t)NB * PCHUNKS * 4);
    int2*   ed2     = (int2*)  alloc((size_t)NE * 8);
    int2*   ed      = (int2*)  alloc((size_t)NE * 8);
    float4* x4      = (float4*)alloc((size_t)NN * 16);
    float4* aggx4   = (float4*)alloc((size_t)NN * 16);
    float*  agg1    = (float*) alloc((size_t)(NN + 128) * C_H1 * 4);  // padded
    float*  pooled  = (float*) alloc((size_t)NG * C_H2 * 4);

    hipMemsetAsync(pooled, 0, (size_t)NG * C_H2 * 4, stream);
    k_hist    <<<PCHUNKS, 256, 0, stream>>>(ei, hist);
    k_colscan0<<<NB, 256, 0, stream>>>(hist, offs, btot);
    k_bbase   <<<1, 256, 0, stream>>>(btot, bbase, row_ptr);
    k_scatterA<<<PCHUNKS, 256, 0, stream>>>(ei, offs, bbase, ed2);
    k_B1      <<<NB, 256, 0, stream>>>(ed2, bbase, dinv, row_ptr);
    k_x4      <<<(NN + 255) / 256, 256, 0, stream>>>(x, x4);
    k_scatterB<<<NB, 512, 0, stream>>>(row_ptr, ed2, dinv, x4, ed, aggx4);
    k_edge1   <<<(NN * C_H1) / 256, 256, 0, stream>>>(row_ptr, ed, aggx4, W1, b1, agg1);
    k_mm2pool <<<MM2_BLOCKS, 256, 0, stream>>>(agg1, W2, b2, batch, pooled);
    k_fc      <<<(NG * C_OUT + 255) / 256, 256, 0, stream>>>(pooled, batch, Wfc, bfc, out);
}

// Round 16
// 236.782 us; speedup vs baseline: 1.0244x; 1.0244x over previous
//
#include <hip/hip_runtime.h>

#define NN 100000     // nodes
#define NE 1600000    // edges
#define NG 512        // graphs
#define C_H1 64
#define C_H2 128
#define C_OUT 2

#define MM2_BLOCKS ((NN + 63) / 64)                   // 1563 (64 nodes/block)
#define NB ((NN + 255) >> 8)                          // 391 dst-buckets of 256 nodes
#define PCHUNKS 512                                   // partition chunks
#define PCHUNK_E (NE / PCHUNKS)                       // 3125 edges per chunk

// ---------------- radix partition phase 1: per-chunk bucket histograms -----------
__global__ void k_hist(const int* __restrict__ ei, int* __restrict__ hist) {
    __shared__ int lh[NB];
    int tid = threadIdx.x;
    int blk = blockIdx.x;
    for (int i = tid; i < NB; i += 256) lh[i] = 0;
    __syncthreads();
    int base = blk * PCHUNK_E;
    for (int e = base + tid; e < base + PCHUNK_E; e += 256)
        atomicAdd(&lh[ei[NE + e] >> 8], 1);
    __syncthreads();
    for (int i = tid; i < NB; i += 256) hist[i * PCHUNKS + blk] = lh[i];
}

// ---------------- phase 2a: per-bucket scan over chunks (bucket-relative) --------
__global__ void k_colscan0(const int* __restrict__ hist, int* __restrict__ offs,
                           int* __restrict__ btot) {
    __shared__ int sh[256];
    int b = blockIdx.x;
    int tid = threadIdx.x;
    int v0 = hist[b * PCHUNKS + 2 * tid];
    int v1 = hist[b * PCHUNKS + 2 * tid + 1];
    sh[tid] = v0 + v1;
    __syncthreads();
    for (int off = 1; off < 256; off <<= 1) {
        int v = (tid >= off) ? sh[tid - off] : 0;
        __syncthreads();
        sh[tid] += v;
        __syncthreads();
    }
    int base = (tid == 0) ? 0 : sh[tid - 1];
    offs[b * PCHUNKS + 2 * tid]     = base;
    offs[b * PCHUNKS + 2 * tid + 1] = base + v0;
    if (tid == 255) btot[b] = sh[255];
}

// ---------------- phase 2b: exclusive scan of 391 bucket totals ------------------
__global__ void k_bbase(const int* __restrict__ btot, int* __restrict__ bbase,
                        int* __restrict__ row_ptr) {
    __shared__ int sh[256];
    int tid = threadIdx.x;
    int v0 = (2 * tid     < NB) ? btot[2 * tid]     : 0;
    int v1 = (2 * tid + 1 < NB) ? btot[2 * tid + 1] : 0;
    sh[tid] = v0 + v1;
    __syncthreads();
    for (int off = 1; off < 256; off <<= 1) {
        int v = (tid >= off) ? sh[tid - off] : 0;
        __syncthreads();
        sh[tid] += v;
        __syncthreads();
    }
    int base = (tid == 0) ? 0 : sh[tid - 1];
    if (2 * tid     < NB) bbase[2 * tid]     = base;
    if (2 * tid + 1 < NB) bbase[2 * tid + 1] = base + v0;
    if (tid == 255) { bbase[NB] = sh[255]; row_ptr[NN] = sh[255]; }   // == NE
}

// ---------------- phase 3: scatter via LDS cursors (no global atomics) -----------
__global__ void k_scatterA(const int* __restrict__ ei, const int* __restrict__ offs,
                           const int* __restrict__ bbase, int2* __restrict__ ed2) {
    __shared__ int lcur[NB];
    int tid = threadIdx.x;
    int blk = blockIdx.x;
    for (int i = tid; i < NB; i += 256) lcur[i] = bbase[i] + offs[i * PCHUNKS + blk];
    __syncthreads();
    int base = blk * PCHUNK_E;
    for (int e = base + tid; e < base + PCHUNK_E; e += 256) {
        int s = ei[e], d = ei[NE + e];
        int pos = atomicAdd(&lcur[d >> 8], 1);     // LDS atomic, low contention
        int2 v; v.x = s; v.y = d;
        ed2[pos] = v;
    }
}

// ---------------- B1: bucket-local degree -> dinv + row_ptr (no global atomics) --
__global__ void k_B1(const int2* __restrict__ ed2, const int* __restrict__ bbase,
                     float* __restrict__ dinv, int* __restrict__ row_ptr) {
    __shared__ int ldeg[256];
    __shared__ int sh[256];
    int b = blockIdx.x;
    int tid = threadIdx.x;
    int lo = b << 8;
    ldeg[tid] = 0;
    __syncthreads();
    int beg = bbase[b], end = bbase[b + 1];
    for (int j = beg + tid; j < end; j += 256)
        atomicAdd(&ldeg[ed2[j].y - lo], 1);
    __syncthreads();
    int d = ldeg[tid];
    int node = lo + tid;
    if (node < NN) dinv[node] = rsqrtf((float)d + 1.0f);
    sh[tid] = d;
    __syncthreads();
    for (int off = 1; off < 256; off <<= 1) {
        int v = (tid >= off) ? sh[tid - off] : 0;
        __syncthreads();
        sh[tid] += v;
        __syncthreads();
    }
    int excl = beg + ((tid == 0) ? 0 : sh[tid - 1]);
    if (node < NN) row_ptr[node] = excl;
}

// ---------------- repack x to float4 rows (16B gathers downstream) ---------------
__global__ void k_x4(const float* __restrict__ x, float4* __restrict__ x4) {
    int n = blockIdx.x * blockDim.x + threadIdx.x;
    if (n >= NN) return;
    float4 v; v.x = x[n * 3]; v.y = x[n * 3 + 1]; v.z = x[n * 3 + 2]; v.w = 0.f;
    x4[n] = v;
}

// ---------------- scatter pass B + fused layer-1 aggregation (512 threads) -------
__global__ void k_scatterB(const int* __restrict__ row_ptr, const int2* __restrict__ ed2,
                           const float* __restrict__ dinv, const float4* __restrict__ x4,
                           int2* __restrict__ ed, float4* __restrict__ aggx4) {
    __shared__ int   lcur[256];
    __shared__ float ldin[256];
    __shared__ float lax[256 * 3];
    int b = blockIdx.x;
    int lo = b << 8;
    int tid = threadIdx.x;
    int node = lo + tid;
    if (tid < 256) {
        lcur[tid] = row_ptr[node < NN ? node : NN];
        ldin[tid] = (node < NN) ? dinv[node] : 0.f;
        lax[tid] = 0.f; lax[256 + tid] = 0.f; lax[512 + tid] = 0.f;
    }
    __syncthreads();
    int seg_beg = row_ptr[lo];
    int hi = lo + 256; if (hi > NN) hi = NN;
    int seg_end = row_ptr[hi];
    for (int j = seg_beg + tid; j < seg_end; j += 512) {
        int2 sd = ed2[j];
        int local = sd.y - lo;
        int pos = atomicAdd(&lcur[local], 1);
        float nrm = dinv[sd.x] * ldin[local];
        int2 v; v.x = sd.x; v.y = __float_as_int(nrm);
        ed[pos] = v;
        float4 xs = x4[sd.x];                          // 16B gather, L2-hot (1.6MB)
        atomicAdd(&lax[local],       nrm * xs.x);      // ds_add_f32
        atomicAdd(&lax[256 + local], nrm * xs.y);
        atomicAdd(&lax[512 + local], nrm * xs.z);
    }
    __syncthreads();
    if (tid < 256 && node < NN) {
        float di = ldin[tid];
        float s2 = di * di;
        float4 xs = x4[node];
        float4 a;
        a.x = lax[tid]       + s2 * xs.x;
        a.y = lax[256 + tid] + s2 * xs.y;
        a.z = lax[512 + tid] + s2 * xs.z;
        a.w = di;                                      // dinv rides along
        aggx4[node] = a;
    }
}

// ---------------- layer 2 aggregate via on-the-fly h1 recompute ------------------
__global__ void k_edge1(const int* __restrict__ row_ptr, const int2* __restrict__ ed,
                        const float4* __restrict__ aggx4,
                        const float* __restrict__ W1, const float* __restrict__ b1,
                        float* __restrict__ agg1) {
    __shared__ float4 lp[256];                        // 64 per wave
    int t = blockIdx.x * 256 + threadIdx.x;           // grid exact: NN*64/256
    int n = t >> 6, c = t & 63;
    int lane = threadIdx.x & 63;
    int wbase = threadIdx.x & 192;                    // wave's LDS base (0,64,128,192)

    float w0 = W1[c], w1 = W1[64 + c], w2 = W1[128 + c], bb = b1[c];
    float4 an = aggx4[n];                             // wave-uniform, .w = dinv
    float hself = fmaxf(fmaf(an.x, w0, fmaf(an.y, w1, fmaf(an.z, w2, bb))), 0.f);
    float acc = an.w * an.w * hself;

    int beg = row_ptr[n], end = row_ptr[n + 1];
    for (int base = beg; base < end; base += 64) {
        int m = end - base; if (m > 64) m = 64;
        if (lane < m) {
            int2 v = ed[base + lane];                 // coalesced 8B
            float4 ax = aggx4[v.x];                   // random 16B, L2-hot
            float4 p; p.x = ax.x; p.y = ax.y; p.z = ax.z; p.w = __int_as_float(v.y);
            lp[wbase + lane] = p;
        }
        int e = 0;
        for (; e + 3 < m; e += 4) {
            float4 p0 = lp[wbase + e];
            float4 p1 = lp[wbase + e + 1];
            float4 p2 = lp[wbase + e + 2];
            float4 p3 = lp[wbase + e + 3];
            float h0  = fmaxf(fmaf(p0.x, w0, fmaf(p0.y, w1, fmaf(p0.z, w2, bb))), 0.f);
            float h1v = fmaxf(fmaf(p1.x, w0, fmaf(p1.y, w1, fmaf(p1.z, w2, bb))), 0.f);
            float h2v = fmaxf(fmaf(p2.x, w0, fmaf(p2.y, w1, fmaf(p2.z, w2, bb))), 0.f);
            float h3v = fmaxf(fmaf(p3.x, w0, fmaf(p3.y, w1, fmaf(p3.z, w2, bb))), 0.f);
            acc = fmaf(p0.w, h0, acc);
            acc = fmaf(p1.w, h1v, acc);
            acc = fmaf(p2.w, h2v, acc);
            acc = fmaf(p3.w, h3v, acc);
        }
        for (; e < m; ++e) {
            float4 p = lp[wbase + e];
            float h = fmaxf(fmaf(p.x, w0, fmaf(p.y, w1, fmaf(p.z, w2, bb))), 0.f);
            acc = fmaf(p.w, h, acc);
        }
    }
    agg1[t] = acc;   // NO bias/relu here: h2 = relu(agg1 @ W2 + b2)
}

// ---------------- fused register-tiled GEMM + pool (v6: W2-LDS + A-global) --------
// Block = 64 nodes x 128 ch, 256 threads, 4x8 micro-tile. W2 staged in LDS (32KB,
// read once from L2); A read from global — block's A slice is 16KB unique -> L1
// serves the 16x re-reads. LDS 34KB -> 4 blocks/CU.
__global__ void k_mm2pool(const float* __restrict__ agg1, const float* __restrict__ W2,
                          const float* __restrict__ b2, const int* __restrict__ batch,
                          float* __restrict__ pooled) {
    __shared__ float wt[C_H1 * C_H2];      // 32 KiB
    __shared__ float lpool[4 * C_H2];      // 2 KiB
    int tid = threadIdx.x;
    {
        const float4* w4 = (const float4*)W2;
        float4* wl = (float4*)wt;
        for (int i = tid; i < (C_H1 * C_H2) / 4; i += 256) wl[i] = w4[i];
        for (int i = tid; i < 4 * C_H2; i += 256) lpool[i] = 0.f;
    }
    __syncthreads();

    int tx = tid & 15;            // channel group: 8 ch
    int my = tid >> 4;            // node group: 4 consecutive nodes
    int c0 = tx * 8;
    int m0 = my * 4;
    const float4* aA = (const float4*)(agg1 + ((size_t)blockIdx.x * 64 + m0) * C_H1);
    // node (m0+i)'s k-chunk k4 lives at aA[i*16 + k4]

    float acc[4][8];
#pragma unroll
    for (int i = 0; i < 4; ++i)
#pragma unroll
        for (int j = 0; j < 8; ++j) acc[i][j] = 0.f;

    for (int k4 = 0; k4 < 16; ++k4) {                 // k = 4*k4 .. 4*k4+3
        float4 af[4];
#pragma unroll
        for (int i = 0; i < 4; ++i) af[i] = aA[i * 16 + k4];   // global, L1-hot
        float4 wf[4][2];
#pragma unroll
        for (int kk = 0; kk < 4; ++kk) {
            wf[kk][0] = *(const float4*)&wt[(k4 * 4 + kk) * C_H2 + c0];
            wf[kk][1] = *(const float4*)&wt[(k4 * 4 + kk) * C_H2 + c0 + 4];
        }
#pragma unroll
        for (int i = 0; i < 4; ++i) {
#pragma unroll
            for (int kk = 0; kk < 4; ++kk) {
                float a = (kk == 0) ? af[i].x : (kk == 1) ? af[i].y
                        : (kk == 2) ? af[i].z : af[i].w;
                acc[i][0] = fmaf(a, wf[kk][0].x, acc[i][0]);
                acc[i][1] = fmaf(a, wf[kk][0].y, acc[i][1]);
                acc[i][2] = fmaf(a, wf[kk][0].z, acc[i][2]);
                acc[i][3] = fmaf(a, wf[kk][0].w, acc[i][3]);
                acc[i][4] = fmaf(a, wf[kk][1].x, acc[i][4]);
                acc[i][5] = fmaf(a, wf[kk][1].y, acc[i][5]);
                acc[i][6] = fmaf(a, wf[kk][1].z, acc[i][6]);
                acc[i][7] = fmaf(a, wf[kk][1].w, acc[i][7]);
            }
        }
    }

    int nbase = blockIdx.x * 64 + m0;
    int gbase = batch[blockIdx.x * 64];                // block-uniform
    int gidx[4];
#pragma unroll
    for (int i = 0; i < 4; ++i)
        gidx[i] = (nbase + i < NN) ? batch[nbase + i] : -1;
    float bias[8];
#pragma unroll
    for (int j = 0; j < 8; ++j) bias[j] = b2[c0 + j];

#pragma unroll
    for (int j = 0; j < 8; ++j) {
        int run_g = -1;
        float rs = 0.f;
#pragma unroll
        for (int i = 0; i < 4; ++i) {
            if (gidx[i] < 0) break;
            float h = fmaxf(acc[i][j] + bias[j], 0.f);
            if (gidx[i] != run_g) {
                if (run_g >= 0) {
                    int slot = run_g - gbase;
                    if (slot < 4) atomicAdd(&lpool[slot * C_H2 + c0 + j], rs);
                    else          atomicAdd(&pooled[(run_g << 7) + c0 + j], rs);
                }
                run_g = gidx[i]; rs = h;
            } else {
                rs += h;
            }
        }
        if (run_g >= 0) {
            int slot = run_g - gbase;
            if (slot < 4) atomicAdd(&lpool[slot * C_H2 + c0 + j], rs);
            else          atomicAdd(&pooled[(run_g << 7) + c0 + j], rs);
        }
    }
    __syncthreads();
    for (int i = tid; i < 4 * C_H2; i += 256) {
        int slot = i >> 7, c = i & 127;
        int g = gbase + slot;
        float v = lpool[i];
        if (g < NG && v != 0.f) atomicAdd(&pooled[(g << 7) + c], v);
    }
}

// ---------------- FC: out = (pooled/cnt) @ Wfc + bfc ----------------
__device__ __forceinline__ int lower_bound(const int* __restrict__ a, int n, int key) {
    int lo = 0, hi = n;
    while (lo < hi) { int mid = (lo + hi) >> 1; if (a[mid] < key) lo = mid + 1; else hi = mid; }
    return lo;
}

__global__ void k_fc(const float* __restrict__ pooled, const int* __restrict__ batch,
                     const float* __restrict__ Wfc, const float* __restrict__ bfc,
                     float* __restrict__ out) {
    int t = blockIdx.x * blockDim.x + threadIdx.x;
    if (t >= NG * C_OUT) return;
    int g = t >> 1, o = t & 1;
    int start = lower_bound(batch, NN, g);
    int end   = lower_bound(batch, NN, g + 1);
    float inv = 1.f / fmaxf((float)(end - start), 1.f);
    float s = bfc[o];
    for (int cc = 0; cc < C_H2; ++cc)
        s = fmaf(pooled[(g << 7) + cc] * inv, Wfc[cc * C_OUT + o], s);
    out[t] = s;
}

extern "C" void kernel_launch(void* const* d_in, const int* in_sizes, int n_in,
                              void* d_out, int out_size, void* d_ws, size_t ws_size,
                              hipStream_t stream) {
    const float* x     = (const float*)d_in[0];
    const int*   ei    = (const int*)d_in[1];   // [2, E]: row0 = src, row1 = dst
    const int*   batch = (const int*)d_in[2];
    const float* W1    = (const float*)d_in[3];
    const float* b1    = (const float*)d_in[4];
    const float* W2    = (const float*)d_in[5];
    const float* b2    = (const float*)d_in[6];
    const float* Wfc   = (const float*)d_in[7];
    const float* bfc   = (const float*)d_in[8];
    float* out = (float*)d_out;

    // workspace carve-out (~58 MB)
    char* p = (char*)d_ws;
    auto alloc = [&](size_t bytes) { char* r = p; p += (bytes + 255) & ~size_t(255); return r; };
    float*  dinv    = (float*) alloc((size_t)NN * 4);
    int*    row_ptr = (int*)   alloc((size_t)(NN + 1) * 4);
    int*    btot    = (int*)   alloc((size_t)NB * 4);
    int*    bbase   = (int*)   alloc((size_t)(NB + 1) * 4);
    int*    hist    = (int*)   alloc((size_t)NB * PCHUNKS * 4);
    int*    offs    = (int*)   alloc((size_t)NB * PCHUNKS * 4);
    int2*   ed2     = (int2*)  alloc((size_t)NE * 8);
    int2*   ed      = (int2*)  alloc((size_t)NE * 8);
    float4* x4      = (float4*)alloc((size_t)NN * 16);
    float4* aggx4   = (float4*)alloc((size_t)NN * 16);
    float*  agg1    = (float*) alloc((size_t)(NN + 128) * C_H1 * 4);  // padded
    float*  pooled  = (float*) alloc((size_t)NG * C_H2 * 4);

    hipMemsetAsync(pooled, 0, (size_t)NG * C_H2 * 4, stream);
    k_hist    <<<PCHUNKS, 256, 0, stream>>>(ei, hist);
    k_colscan0<<<NB, 256, 0, stream>>>(hist, offs, btot);
    k_bbase   <<<1, 256, 0, stream>>>(btot, bbase, row_ptr);
    k_scatterA<<<PCHUNKS, 256, 0, stream>>>(ei, offs, bbase, ed2);
    k_B1      <<<NB, 256, 0, stream>>>(ed2, bbase, dinv, row_ptr);
    k_x4      <<<(NN + 255) / 256, 256, 0, stream>>>(x, x4);
    k_scatterB<<<NB, 512, 0, stream>>>(row_ptr, ed2, dinv, x4, ed, aggx4);
    k_edge1   <<<(NN * C_H1) / 256, 256, 0, stream>>>(row_ptr, ed, aggx4, W1, b1, agg1);
    k_mm2pool <<<MM2_BLOCKS, 256, 0, stream>>>(agg1, W2, b2, batch, pooled);
    k_fc      <<<(NG * C_OUT + 255) / 256, 256, 0, stream>>>(pooled, batch, Wfc, bfc, out);
}

// Round 17
// 232.941 us; speedup vs baseline: 1.0413x; 1.0165x over previous
//
#include <hip/hip_runtime.h>

#define NN 100000     // nodes
#define NE 1600000    // edges
#define NG 512        // graphs
#define C_H1 64
#define C_H2 128
#define C_OUT 2

#define MM2_BLOCKS ((NN + 127) / 128)                 // 782 (128 nodes/block)
#define NB ((NN + 255) >> 8)                          // 391 dst-buckets of 256 nodes
#define PCHUNKS 512                                   // partition chunks
#define PCHUNK_E (NE / PCHUNKS)                       // 3125 edges per chunk

// ---------------- radix partition phase 1: per-chunk bucket histograms -----------
__global__ void k_hist(const int* __restrict__ ei, int* __restrict__ hist) {
    __shared__ int lh[NB];
    int tid = threadIdx.x;
    int blk = blockIdx.x;
    for (int i = tid; i < NB; i += 256) lh[i] = 0;
    __syncthreads();
    int base = blk * PCHUNK_E;
    for (int e = base + tid; e < base + PCHUNK_E; e += 256)
        atomicAdd(&lh[ei[NE + e] >> 8], 1);
    __syncthreads();
    for (int i = tid; i < NB; i += 256) hist[i * PCHUNKS + blk] = lh[i];
}

// ---------------- phase 2a: per-bucket scan over chunks (bucket-relative) --------
__global__ void k_colscan0(const int* __restrict__ hist, int* __restrict__ offs,
                           int* __restrict__ btot) {
    __shared__ int sh[256];
    int b = blockIdx.x;
    int tid = threadIdx.x;
    int v0 = hist[b * PCHUNKS + 2 * tid];
    int v1 = hist[b * PCHUNKS + 2 * tid + 1];
    sh[tid] = v0 + v1;
    __syncthreads();
    for (int off = 1; off < 256; off <<= 1) {
        int v = (tid >= off) ? sh[tid - off] : 0;
        __syncthreads();
        sh[tid] += v;
        __syncthreads();
    }
    int base = (tid == 0) ? 0 : sh[tid - 1];
    offs[b * PCHUNKS + 2 * tid]     = base;
    offs[b * PCHUNKS + 2 * tid + 1] = base + v0;
    if (tid == 255) btot[b] = sh[255];
}

// ---------------- phase 2b: exclusive scan of 391 bucket totals ------------------
__global__ void k_bbase(const int* __restrict__ btot, int* __restrict__ bbase,
                        int* __restrict__ row_ptr) {
    __shared__ int sh[256];
    int tid = threadIdx.x;
    int v0 = (2 * tid     < NB) ? btot[2 * tid]     : 0;
    int v1 = (2 * tid + 1 < NB) ? btot[2 * tid + 1] : 0;
    sh[tid] = v0 + v1;
    __syncthreads();
    for (int off = 1; off < 256; off <<= 1) {
        int v = (tid >= off) ? sh[tid - off] : 0;
        __syncthreads();
        sh[tid] += v;
        __syncthreads();
    }
    int base = (tid == 0) ? 0 : sh[tid - 1];
    if (2 * tid     < NB) bbase[2 * tid]     = base;
    if (2 * tid + 1 < NB) bbase[2 * tid + 1] = base + v0;
    if (tid == 255) { bbase[NB] = sh[255]; row_ptr[NN] = sh[255]; }   // == NE
}

// ---------------- phase 3: scatter via LDS cursors (no global atomics) -----------
__global__ void k_scatterA(const int* __restrict__ ei, const int* __restrict__ offs,
                           const int* __restrict__ bbase, int2* __restrict__ ed2) {
    __shared__ int lcur[NB];
    int tid = threadIdx.x;
    int blk = blockIdx.x;
    for (int i = tid; i < NB; i += 256) lcur[i] = bbase[i] + offs[i * PCHUNKS + blk];
    __syncthreads();
    int base = blk * PCHUNK_E;
    for (int e = base + tid; e < base + PCHUNK_E; e += 256) {
        int s = ei[e], d = ei[NE + e];
        int pos = atomicAdd(&lcur[d >> 8], 1);     // LDS atomic, low contention
        int2 v; v.x = s; v.y = d;
        ed2[pos] = v;
    }
}

// ---------------- B1: bucket-local degree -> dinv + row_ptr (no global atomics) --
__global__ void k_B1(const int2* __restrict__ ed2, const int* __restrict__ bbase,
                     float* __restrict__ dinv, int* __restrict__ row_ptr) {
    __shared__ int ldeg[256];
    __shared__ int sh[256];
    int b = blockIdx.x;
    int tid = threadIdx.x;
    int lo = b << 8;
    ldeg[tid] = 0;
    __syncthreads();
    int beg = bbase[b], end = bbase[b + 1];
    for (int j = beg + tid; j < end; j += 256)
        atomicAdd(&ldeg[ed2[j].y - lo], 1);
    __syncthreads();
    int d = ldeg[tid];
    int node = lo + tid;
    if (node < NN) dinv[node] = rsqrtf((float)d + 1.0f);
    sh[tid] = d;
    __syncthreads();
    for (int off = 1; off < 256; off <<= 1) {
        int v = (tid >= off) ? sh[tid - off] : 0;
        __syncthreads();
        sh[tid] += v;
        __syncthreads();
    }
    int excl = beg + ((tid == 0) ? 0 : sh[tid - 1]);
    if (node < NN) row_ptr[node] = excl;
}

// ---------------- repack x to float4 rows (16B gathers downstream) ---------------
__global__ void k_x4(const float* __restrict__ x, float4* __restrict__ x4) {
    int n = blockIdx.x * blockDim.x + threadIdx.x;
    if (n >= NN) return;
    float4 v; v.x = x[n * 3]; v.y = x[n * 3 + 1]; v.z = x[n * 3 + 2]; v.w = 0.f;
    x4[n] = v;
}

// ---------------- scatter pass B + fused layer-1 aggregation (512 threads) -------
__global__ void k_scatterB(const int* __restrict__ row_ptr, const int2* __restrict__ ed2,
                           const float* __restrict__ dinv, const float4* __restrict__ x4,
                           int2* __restrict__ ed, float4* __restrict__ aggx4) {
    __shared__ int   lcur[256];
    __shared__ float ldin[256];
    __shared__ float lax[256 * 3];
    int b = blockIdx.x;
    int lo = b << 8;
    int tid = threadIdx.x;
    int node = lo + tid;
    if (tid < 256) {
        lcur[tid] = row_ptr[node < NN ? node : NN];
        ldin[tid] = (node < NN) ? dinv[node] : 0.f;
        lax[tid] = 0.f; lax[256 + tid] = 0.f; lax[512 + tid] = 0.f;
    }
    __syncthreads();
    int seg_beg = row_ptr[lo];
    int hi = lo + 256; if (hi > NN) hi = NN;
    int seg_end = row_ptr[hi];
    for (int j = seg_beg + tid; j < seg_end; j += 512) {
        int2 sd = ed2[j];
        int local = sd.y - lo;
        int pos = atomicAdd(&lcur[local], 1);
        float nrm = dinv[sd.x] * ldin[local];
        int2 v; v.x = sd.x; v.y = __float_as_int(nrm);
        ed[pos] = v;
        float4 xs = x4[sd.x];                          // 16B gather, L2-hot (1.6MB)
        atomicAdd(&lax[local],       nrm * xs.x);      // ds_add_f32
        atomicAdd(&lax[256 + local], nrm * xs.y);
        atomicAdd(&lax[512 + local], nrm * xs.z);
    }
    __syncthreads();
    if (tid < 256 && node < NN) {
        float di = ldin[tid];
        float s2 = di * di;
        float4 xs = x4[node];
        float4 a;
        a.x = lax[tid]       + s2 * xs.x;
        a.y = lax[256 + tid] + s2 * xs.y;
        a.z = lax[512 + tid] + s2 * xs.z;
        a.w = di;                                      // dinv rides along
        aggx4[node] = a;
    }
}

// ---------------- layer 2 aggregate via on-the-fly h1 recompute ------------------
__global__ void k_edge1(const int* __restrict__ row_ptr, const int2* __restrict__ ed,
                        const float4* __restrict__ aggx4,
                        const float* __restrict__ W1, const float* __restrict__ b1,
                        float* __restrict__ agg1) {
    __shared__ float4 lp[256];                        // 64 per wave
    int t = blockIdx.x * 256 + threadIdx.x;           // grid exact: NN*64/256
    int n = t >> 6, c = t & 63;
    int lane = threadIdx.x & 63;
    int wbase = threadIdx.x & 192;                    // wave's LDS base (0,64,128,192)

    float w0 = W1[c], w1 = W1[64 + c], w2 = W1[128 + c], bb = b1[c];
    float4 an = aggx4[n];                             // wave-uniform, .w = dinv
    float hself = fmaxf(fmaf(an.x, w0, fmaf(an.y, w1, fmaf(an.z, w2, bb))), 0.f);
    float acc = an.w * an.w * hself;

    int beg = row_ptr[n], end = row_ptr[n + 1];
    for (int base = beg; base < end; base += 64) {
        int m = end - base; if (m > 64) m = 64;
        if (lane < m) {
            int2 v = ed[base + lane];                 // coalesced 8B
            float4 ax = aggx4[v.x];                   // random 16B, L2-hot
            float4 p; p.x = ax.x; p.y = ax.y; p.z = ax.z; p.w = __int_as_float(v.y);
            lp[wbase + lane] = p;
        }
        int e = 0;
        for (; e + 3 < m; e += 4) {
            float4 p0 = lp[wbase + e];
            float4 p1 = lp[wbase + e + 1];
            float4 p2 = lp[wbase + e + 2];
            float4 p3 = lp[wbase + e + 3];
            float h0  = fmaxf(fmaf(p0.x, w0, fmaf(p0.y, w1, fmaf(p0.z, w2, bb))), 0.f);
            float h1v = fmaxf(fmaf(p1.x, w0, fmaf(p1.y, w1, fmaf(p1.z, w2, bb))), 0.f);
            float h2v = fmaxf(fmaf(p2.x, w0, fmaf(p2.y, w1, fmaf(p2.z, w2, bb))), 0.f);
            float h3v = fmaxf(fmaf(p3.x, w0, fmaf(p3.y, w1, fmaf(p3.z, w2, bb))), 0.f);
            acc = fmaf(p0.w, h0, acc);
            acc = fmaf(p1.w, h1v, acc);
            acc = fmaf(p2.w, h2v, acc);
            acc = fmaf(p3.w, h3v, acc);
        }
        for (; e < m; ++e) {
            float4 p = lp[wbase + e];
            float h = fmaxf(fmaf(p.x, w0, fmaf(p.y, w1, fmaf(p.z, w2, bb))), 0.f);
            acc = fmaf(p.w, h, acc);
        }
    }
    agg1[t] = acc;   // NO bias/relu here: h2 = relu(agg1 @ W2 + b2)
}

// ---------------- fused register-tiled GEMM + pool (v7) ---------------------------
// Block = 128 nodes, 256 threads, 8 nodes x 8 ch per thread. W2 in LDS; A from
// global (L1-hot). Channel split {tx*4, tx*4+64}: lane stride 16B -> 2-way bank
// aliasing (free). 8 LDS reads per 256 FMAs -> FMA-bound.
__global__ void k_mm2pool(const float* __restrict__ agg1, const float* __restrict__ W2,
                          const float* __restrict__ b2, const int* __restrict__ batch,
                          float* __restrict__ pooled) {
    __shared__ float wt[C_H1 * C_H2];      // 32 KiB
    __shared__ float lpool[4 * C_H2];      // 2 KiB
    int tid = threadIdx.x;
    {
        const float4* w4 = (const float4*)W2;
        float4* wl = (float4*)wt;
        for (int i = tid; i < (C_H1 * C_H2) / 4; i += 256) wl[i] = w4[i];
        for (int i = tid; i < 4 * C_H2; i += 256) lpool[i] = 0.f;
    }
    __syncthreads();

    int tx = tid & 15;            // channel group: {cA..cA+3, cB..cB+3}
    int my = tid >> 4;            // node group: 8 consecutive nodes
    int cA = tx * 4;
    int cB = tx * 4 + 64;
    int m0 = my * 8;
    const float4* aA = (const float4*)(agg1 + ((size_t)blockIdx.x * 128 + m0) * C_H1);
    // node (m0+i)'s k-chunk k4 lives at aA[i*16 + k4]

    float acc[8][8];              // [node][ch]: 0..3 -> cA+j, 4..7 -> cB+j-4
#pragma unroll
    for (int i = 0; i < 8; ++i)
#pragma unroll
        for (int j = 0; j < 8; ++j) acc[i][j] = 0.f;

    for (int k4 = 0; k4 < 16; ++k4) {                 // k = 4*k4 .. 4*k4+3
        float4 af[8];
#pragma unroll
        for (int i = 0; i < 8; ++i) af[i] = aA[i * 16 + k4];   // global, L1-hot
        float4 wfA[4], wfB[4];
#pragma unroll
        for (int kk = 0; kk < 4; ++kk) {
            wfA[kk] = *(const float4*)&wt[(k4 * 4 + kk) * C_H2 + cA];   // 2-way, free
            wfB[kk] = *(const float4*)&wt[(k4 * 4 + kk) * C_H2 + cB];
        }
#pragma unroll
        for (int i = 0; i < 8; ++i) {
#pragma unroll
            for (int kk = 0; kk < 4; ++kk) {
                float a = (kk == 0) ? af[i].x : (kk == 1) ? af[i].y
                        : (kk == 2) ? af[i].z : af[i].w;
                acc[i][0] = fmaf(a, wfA[kk].x, acc[i][0]);
                acc[i][1] = fmaf(a, wfA[kk].y, acc[i][1]);
                acc[i][2] = fmaf(a, wfA[kk].z, acc[i][2]);
                acc[i][3] = fmaf(a, wfA[kk].w, acc[i][3]);
                acc[i][4] = fmaf(a, wfB[kk].x, acc[i][4]);
                acc[i][5] = fmaf(a, wfB[kk].y, acc[i][5]);
                acc[i][6] = fmaf(a, wfB[kk].z, acc[i][6]);
                acc[i][7] = fmaf(a, wfB[kk].w, acc[i][7]);
            }
        }
    }

    int nbase = blockIdx.x * 128 + m0;
    int gbase = batch[blockIdx.x * 128];               // block-uniform
    int gidx[8];
#pragma unroll
    for (int i = 0; i < 8; ++i)
        gidx[i] = (nbase + i < NN) ? batch[nbase + i] : -1;
    float biasv[8];
#pragma unroll
    for (int j = 0; j < 4; ++j) { biasv[j] = b2[cA + j]; biasv[j + 4] = b2[cB + j]; }

#pragma unroll
    for (int j = 0; j < 8; ++j) {
        int cj = (j < 4) ? (cA + j) : (cB + j - 4);
        int run_g = -1;
        float rs = 0.f;
#pragma unroll
        for (int i = 0; i < 8; ++i) {
            if (gidx[i] < 0) break;
            float h = fmaxf(acc[i][j] + biasv[j], 0.f);
            if (gidx[i] != run_g) {
                if (run_g >= 0) {
                    int slot = run_g - gbase;
                    if (slot < 4) atomicAdd(&lpool[slot * C_H2 + cj], rs);
                    else          atomicAdd(&pooled[(run_g << 7) + cj], rs);
                }
                run_g = gidx[i]; rs = h;
            } else {
                rs += h;
            }
        }
        if (run_g >= 0) {
            int slot = run_g - gbase;
            if (slot < 4) atomicAdd(&lpool[slot * C_H2 + cj], rs);
            else          atomicAdd(&pooled[(run_g << 7) + cj], rs);
        }
    }
    __syncthreads();
    for (int i = tid; i < 4 * C_H2; i += 256) {
        int slot = i >> 7, c = i & 127;
        int g = gbase + slot;
        float v = lpool[i];
        if (g < NG && v != 0.f) atomicAdd(&pooled[(g << 7) + c], v);
    }
}

// ---------------- FC: out = (pooled/cnt) @ Wfc + bfc ----------------
__device__ __forceinline__ int lower_bound(const int* __restrict__ a, int n, int key) {
    int lo = 0, hi = n;
    while (lo < hi) { int mid = (lo + hi) >> 1; if (a[mid] < key) lo = mid + 1; else hi = mid; }
    return lo;
}

__global__ void k_fc(const float* __restrict__ pooled, const int* __restrict__ batch,
                     const float* __restrict__ Wfc, const float* __restrict__ bfc,
                     float* __restrict__ out) {
    int t = blockIdx.x * blockDim.x + threadIdx.x;
    if (t >= NG * C_OUT) return;
    int g = t >> 1, o = t & 1;
    int start = lower_bound(batch, NN, g);
    int end   = lower_bound(batch, NN, g + 1);
    float inv = 1.f / fmaxf((float)(end - start), 1.f);
    float s = bfc[o];
    for (int cc = 0; cc < C_H2; ++cc)
        s = fmaf(pooled[(g << 7) + cc] * inv, Wfc[cc * C_OUT + o], s);
    out[t] = s;
}

extern "C" void kernel_launch(void* const* d_in, const int* in_sizes, int n_in,
                              void* d_out, int out_size, void* d_ws, size_t ws_size,
                              hipStream_t stream) {
    const float* x     = (const float*)d_in[0];
    const int*   ei    = (const int*)d_in[1];   // [2, E]: row0 = src, row1 = dst
    const int*   batch = (const int*)d_in[2];
    const float* W1    = (const float*)d_in[3];
    const float* b1    = (const float*)d_in[4];
    const float* W2    = (const float*)d_in[5];
    const float* b2    = (const float*)d_in[6];
    const float* Wfc   = (const float*)d_in[7];
    const float* bfc   = (const float*)d_in[8];
    float* out = (float*)d_out;

    // workspace carve-out (~58 MB)
    char* p = (char*)d_ws;
    auto alloc = [&](size_t bytes) { char* r = p; p += (bytes + 255) & ~size_t(255); return r; };
    float*  dinv    = (float*) alloc((size_t)NN * 4);
    int*    row_ptr = (int*)   alloc((size_t)(NN + 1) * 4);
    int*    btot    = (int*)   alloc((size_t)NB * 4);
    int*    bbase   = (int*)   alloc((size_t)(NB + 1) * 4);
    int*    hist    = (int*)   alloc((size_t)NB * PCHUNKS * 4);
    int*    offs    = (int*)   alloc((size_t)NB * PCHUNKS * 4);
    int2*   ed2     = (int2*)  alloc((size_t)NE * 8);
    int2*   ed      = (int2*)  alloc((size_t)NE * 8);
    float4* x4      = (float4*)alloc((size_t)NN * 16);
    float4* aggx4   = (float4*)alloc((size_t)NN * 16);
    float*  agg1    = (float*) alloc((size_t)(NN + 128) * C_H1 * 4);  // padded
    float*  pooled  = (float*) alloc((size_t)NG * C_H2 * 4);

    hipMemsetAsync(pooled, 0, (size_t)NG * C_H2 * 4, stream);
    k_hist    <<<PCHUNKS, 256, 0, stream>>>(ei, hist);
    k_colscan0<<<NB, 256, 0, stream>>>(hist, offs, btot);
    k_bbase   <<<1, 256, 0, stream>>>(btot, bbase, row_ptr);
    k_scatterA<<<PCHUNKS, 256, 0, stream>>>(ei, offs, bbase, ed2);
    k_B1      <<<NB, 256, 0, stream>>>(ed2, bbase, dinv, row_ptr);
    k_x4      <<<(NN + 255) / 256, 256, 0, stream>>>(x, x4);
    k_scatterB<<<NB, 512, 0, stream>>>(row_ptr, ed2, dinv, x4, ed, aggx4);
    k_edge1   <<<(NN * C_H1) / 256, 256, 0, stream>>>(row_ptr, ed, aggx4, W1, b1, agg1);
    k_mm2pool <<<MM2_BLOCKS, 256, 0, stream>>>(agg1, W2, b2, batch, pooled);
    k_fc      <<<(NG * C_OUT + 255) / 256, 256, 0, stream>>>(pooled, batch, Wfc, bfc, out);
}